// Round 4
// baseline (371.700 us; speedup 1.0000x reference)
//
#include <hip/hip_runtime.h>
#include <math.h>

// CapsuleLayer dynamic routing, fp32 in/out. B=256, I=2048, K=8, J=10, D=16.
// MFMA path (R3, validated) + R4 changes:
//  - 8 i per wave, grid (64,16)=1024 blocks -> 4 blocks/CU (was 2), launch_bounds(256,4).
//  - no atomics: round kernels write per-block partials p[bt][128][2560]; fused
//    reduce+squash kernel sums 128 chunks and squashes (no zero_kernel needed).
//  - softmax without max-subtraction (|logit| is O(1); exp cannot overflow), rcp approx.
// mfma_f32_16x16x32_bf16: C/D col=lane&15=b, row=(lane>>4)*4+reg=d. Round 1 packs
// 4 i's into K=32 (kc=q*8+k, i_local=q); rounds 2/3 use k=8 of 32 (quads 1..3 zero).
// Routing logits are linear in accumulated v (round 3 uses v1+v2) -> no logit buffer.
//
// ws: vT f32[40960] | p f32[16*128*2560] | xTb bf16[I*B*K] | Wb bf16[J*I*D*K] (~34.8 MB)

#define BB 256
#define II 2048
#define KK 8
#define JJ 10
#define DD 16

typedef __attribute__((ext_vector_type(4))) float f32x4;
typedef __attribute__((ext_vector_type(8))) short short8;

__device__ __forceinline__ short f2bf(float f) {
    union { float f; unsigned u; } v; v.f = f;
    unsigned r = v.u + 0x7FFFu + ((v.u >> 16) & 1u);   // RNE
    return (short)(r >> 16);
}

// W fp32 [j,i,d,k] -> Wb bf16 same layout (k contiguous = A-frag rows).
__global__ __launch_bounds__(256) void cast_w_kernel(const float* __restrict__ W,
                                                     short* __restrict__ Wb) {
    const int idx = blockIdx.x * blockDim.x + threadIdx.x;
    const float4* src = (const float4*)(W + (size_t)idx * 8);
    const float4 a = src[0], b = src[1];
    short8 o;
    o[0] = f2bf(a.x); o[1] = f2bf(a.y); o[2] = f2bf(a.z); o[3] = f2bf(a.w);
    o[4] = f2bf(b.x); o[5] = f2bf(b.y); o[6] = f2bf(b.z); o[7] = f2bf(b.w);
    *(short8*)(Wb + (size_t)idx * 8) = o;
}

// x fp32 [b,i,k] -> xTb bf16 [i,b,k], LDS-tiled, coalesced both sides.
__global__ __launch_bounds__(256) void trans_x_kernel(const float* __restrict__ x,
                                                      short* __restrict__ xTb) {
    __shared__ float4 tile[8 * 66];
    const int t = threadIdx.x;
    const int b0 = blockIdx.y * 32, i0 = blockIdx.x * 8;
    {
        const int lb = t >> 3, li = t & 7;
        const float4* src = (const float4*)(x + ((b0 + lb) * II + (i0 + li)) * KK);
        tile[li * 66 + lb * 2 + 0] = src[0];
        tile[li * 66 + lb * 2 + 1] = src[1];
    }
    __syncthreads();
    {
        const int ri = t >> 5, rb = t & 31;
        const float4 p0 = tile[ri * 66 + rb * 2 + 0];
        const float4 p1 = tile[ri * 66 + rb * 2 + 1];
        short8 o;
        o[0] = f2bf(p0.x); o[1] = f2bf(p0.y); o[2] = f2bf(p0.z); o[3] = f2bf(p0.w);
        o[4] = f2bf(p1.x); o[5] = f2bf(p1.y); o[6] = f2bf(p1.z); o[7] = f2bf(p1.w);
        *(short8*)(xTb + ((size_t)(i0 + ri) * BB + (b0 + rb)) * KK) = o;
    }
}

// One routing round. grid (64, 16), block 256 (4 waves), 8 i per wave.
// Writes partials p[bt][chunk=blockIdx.x*2+wv][l], l = (j*16+d)*16 + bc.
template <int USE_C>
__global__ __launch_bounds__(256, 4) void round_mfma(
    const short* __restrict__ xTb, const short* __restrict__ Wb,
    const float* __restrict__ vT, float* __restrict__ p)
{
    __shared__ float s_lds[2][JJ * DD * 16];
    const int t = threadIdx.x;
    const int lane = t & 63, wv = t >> 6;
    const int col = lane & 15, q = lane >> 4;
    const int b0 = blockIdx.y * 16;
    const int ibase = (blockIdx.x * 4 + wv) * 8;

    f32x4 sfrag[JJ];
#pragma unroll
    for (int j = 0; j < JJ; ++j) sfrag[j] = (f32x4){0.f, 0.f, 0.f, 0.f};

    if (USE_C) {
        float vfrag[JJ][4];
#pragma unroll
        for (int j = 0; j < JJ; ++j)
#pragma unroll
            for (int r = 0; r < 4; ++r)
                vfrag[j][r] = vT[(j * DD + q * 4 + r) * BB + b0 + col];

        short8 A[JJ];
        short8 Bf = (short8){0, 0, 0, 0, 0, 0, 0, 0};
#pragma unroll
        for (int j = 0; j < JJ; ++j) A[j] = (short8){0, 0, 0, 0, 0, 0, 0, 0};

        for (int ii = 0; ii < 8; ++ii) {
            const int i = ibase + ii;
            if (q == 0) {   // kc 0..7 real, quads 1..3 stay zero (k-pad 8->32)
                Bf = *(const short8*)(xTb + ((size_t)i * BB + b0 + col) * KK);
#pragma unroll
                for (int j = 0; j < JJ; ++j)
                    A[j] = *(const short8*)(Wb + (((size_t)j * II + i) * DD + col) * KK);
            }
            f32x4 U[JJ];
#pragma unroll
            for (int j = 0; j < JJ; ++j)
                U[j] = __builtin_amdgcn_mfma_f32_16x16x32_bf16(
                    A[j], Bf, (f32x4){0.f, 0.f, 0.f, 0.f}, 0, 0, 0);
            float L[JJ];
#pragma unroll
            for (int j = 0; j < JJ; ++j)
                L[j] = vfrag[j][0] * U[j][0] + vfrag[j][1] * U[j][1]
                     + vfrag[j][2] * U[j][2] + vfrag[j][3] * U[j][3];
#pragma unroll
            for (int j = 0; j < JJ; ++j) {   // reduce over the 4 d-quads (same b col)
                L[j] += __shfl_xor(L[j], 16, 64);
                L[j] += __shfl_xor(L[j], 32, 64);
            }
            // softmax without max-subtraction: |L| is O(1), exp cannot overflow
            float sum = 0.f;
#pragma unroll
            for (int j = 0; j < JJ; ++j) { L[j] = __expf(L[j]); sum += L[j]; }
            const float inv = __builtin_amdgcn_rcpf(sum);
#pragma unroll
            for (int j = 0; j < JJ; ++j) {
                const float c = L[j] * inv;
#pragma unroll
                for (int r = 0; r < 4; ++r) sfrag[j][r] += c * U[j][r];
            }
        }
    } else {
        // round 1: sum_i U. Pack 4 i's per MFMA: kc = q*8 + k -> i_local = q.
        for (int s = 0; s < 2; ++s) {
            const int i = ibase + s * 4 + q;
            const short8 Bf = *(const short8*)(xTb + ((size_t)i * BB + b0 + col) * KK);
#pragma unroll
            for (int j = 0; j < JJ; ++j) {
                const short8 A = *(const short8*)(Wb + (((size_t)j * II + i) * DD + col) * KK);
                sfrag[j] = __builtin_amdgcn_mfma_f32_16x16x32_bf16(A, Bf, sfrag[j], 0, 0, 0);
            }
        }
    }

    // cross-wave pair-reduce: waves 2,3 -> LDS; waves 0,1 add and write partial chunk
    if (wv >= 2) {
#pragma unroll
        for (int j = 0; j < JJ; ++j)
#pragma unroll
            for (int r = 0; r < 4; ++r)
                s_lds[wv - 2][(j * DD + q * 4 + r) * 16 + col] = sfrag[j][r];
    }
    __syncthreads();
    if (wv < 2) {
        const int ch = blockIdx.x * 2 + wv;
        float* pp = p + ((size_t)blockIdx.y * 128 + ch) * (JJ * DD * 16);
#pragma unroll
        for (int j = 0; j < JJ; ++j)
#pragma unroll
            for (int r = 0; r < 4; ++r) {
                const int l = (j * DD + q * 4 + r) * 16 + col;
                pp[l] = sfrag[j][r] + s_lds[wv][l];
            }
    }
}

// Fused reduce + squash. grid (10 j, 16 bt), block 256 (t = d*16 + bc).
// MODE 0: vT = squash(scale*s)   MODE 1: vT += squash(s)   MODE 2: out = squash(s)
template <int MODE>
__global__ __launch_bounds__(256) void rs_kernel(const float* __restrict__ p,
                                                 float* __restrict__ vT,
                                                 float* __restrict__ out, float scale) {
    __shared__ float red[256];
    __shared__ float cf[16];
    const int t = threadIdx.x;
    const int j = blockIdx.x, bt = blockIdx.y;
    const int d = t >> 4, bc = t & 15;

    const float* pp = p + (size_t)bt * 128 * (JJ * DD * 16) + j * 256 + t;
    float sum = 0.f;
#pragma unroll 8
    for (int ch = 0; ch < 128; ++ch) sum += pp[(size_t)ch * (JJ * DD * 16)];
    const float s = sum * scale;

    red[t] = s;
    __syncthreads();
    if (t < 16) {
        float ss = 0.f;
#pragma unroll
        for (int dd = 0; dd < DD; ++dd) {
            const float v = red[dd * 16 + t];
            ss += v * v;
        }
        cf[t] = ss / (1.f + ss) / sqrtf(ss + 1e-7f);
    }
    __syncthreads();
    const float v = cf[bc] * s;
    if (MODE == 0) vT[(j * DD + d) * BB + bt * 16 + bc] = v;
    if (MODE == 1) vT[(j * DD + d) * BB + bt * 16 + bc] += v;
    if (MODE == 2) out[((bt * 16 + bc) * JJ + j) * DD + d] = v;
}

// ---------------- fallback path (round-1 passing kernel, 365us) ----------------
#define IT_OLD 32
#define BT_OLD 16

__global__ __launch_bounds__(256) void zero_kernel(float* __restrict__ p, int n) {
    int idx = blockIdx.x * blockDim.x + threadIdx.x;
    if (idx < n) p[idx] = 0.f;
}

__global__ __launch_bounds__(256) void squash_old(float* __restrict__ s_acc,
                                                  float* __restrict__ dst, float scale,
                                                  int add_to_dst, int zero_src) {
    int idx = blockIdx.x * blockDim.x + threadIdx.x;
    if (idx >= BB * JJ) return;
    float s[DD];
    float ss = 0.f;
#pragma unroll
    for (int d = 0; d < DD; ++d) {
        s[d] = s_acc[idx * DD + d] * scale;
        ss += s[d] * s[d];
    }
    const float coef = ss / (1.f + ss) / sqrtf(ss + 1e-7f);
#pragma unroll
    for (int d = 0; d < DD; ++d) {
        const float vv = coef * s[d];
        if (add_to_dst) dst[idx * DD + d] += vv;
        else            dst[idx * DD + d] = vv;
        if (zero_src)   s_acc[idx * DD + d] = 0.f;
    }
}

__global__ __launch_bounds__(256) void round1_old(const float* __restrict__ x,
                                                  const float* __restrict__ W,
                                                  float* __restrict__ s_acc) {
    const int t = threadIdx.x;
    const int d = t & 15;
    const int bq = t >> 4;
    const int b = blockIdx.y * BT_OLD + bq;
    const int i0 = blockIdx.x * IT_OLD;
    float acc[JJ];
#pragma unroll
    for (int j = 0; j < JJ; ++j) acc[j] = 0.f;
    for (int ii = 0; ii < IT_OLD; ++ii) {
        const int i = i0 + ii;
        const float* xp = x + ((b * II) + i) * KK;
        const float4 xa = *(const float4*)(xp);
        const float4 xb = *(const float4*)(xp + 4);
#pragma unroll
        for (int j = 0; j < JJ; ++j) {
            const float* wp = W + (((j * II + i) * DD + d) * KK);
            const float4 w0 = *(const float4*)(wp);
            const float4 w1 = *(const float4*)(wp + 4);
            acc[j] += w0.x*xa.x + w0.y*xa.y + w0.z*xa.z + w0.w*xa.w
                    + w1.x*xb.x + w1.y*xb.y + w1.z*xb.z + w1.w*xb.w;
        }
    }
#pragma unroll
    for (int j = 0; j < JJ; ++j)
        atomicAdd(&s_acc[(b * JJ + j) * DD + d], acc[j]);
}

__global__ __launch_bounds__(256) void round_old(const float* __restrict__ x,
                                                 const float* __restrict__ W,
                                                 const float* __restrict__ v,
                                                 float* __restrict__ s_acc) {
    const int t = threadIdx.x;
    const int d = t & 15;
    const int bq = t >> 4;
    const int b = blockIdx.y * BT_OLD + bq;
    const int i0 = blockIdx.x * IT_OLD;
    float vr[JJ], acc[JJ];
#pragma unroll
    for (int j = 0; j < JJ; ++j) {
        vr[j] = v[(b * JJ + j) * DD + d];
        acc[j] = 0.f;
    }
    for (int ii = 0; ii < IT_OLD; ++ii) {
        const int i = i0 + ii;
        const float* xp = x + ((b * II) + i) * KK;
        const float4 xa = *(const float4*)(xp);
        const float4 xb = *(const float4*)(xp + 4);
        float U[JJ], L[JJ];
#pragma unroll
        for (int j = 0; j < JJ; ++j) {
            const float* wp = W + (((j * II + i) * DD + d) * KK);
            const float4 w0 = *(const float4*)(wp);
            const float4 w1 = *(const float4*)(wp + 4);
            U[j] = w0.x*xa.x + w0.y*xa.y + w0.z*xa.z + w0.w*xa.w
                 + w1.x*xb.x + w1.y*xb.y + w1.z*xb.z + w1.w*xb.w;
            L[j] = vr[j] * U[j];
        }
#pragma unroll
        for (int m = 8; m >= 1; m >>= 1) {
#pragma unroll
            for (int j = 0; j < JJ; ++j) L[j] += __shfl_xor(L[j], m, 64);
        }
        float mx = L[0];
#pragma unroll
        for (int j = 1; j < JJ; ++j) mx = fmaxf(mx, L[j]);
        float sum = 0.f;
#pragma unroll
        for (int j = 0; j < JJ; ++j) { L[j] = __expf(L[j] - mx); sum += L[j]; }
        const float inv = 1.f / sum;
#pragma unroll
        for (int j = 0; j < JJ; ++j) acc[j] += (L[j] * inv) * U[j];
    }
#pragma unroll
    for (int j = 0; j < JJ; ++j)
        atomicAdd(&s_acc[(b * JJ + j) * DD + d], acc[j]);
}

extern "C" void kernel_launch(void* const* d_in, const int* in_sizes, int n_in,
                              void* d_out, int out_size, void* d_ws, size_t ws_size,
                              hipStream_t stream) {
    const float* x = (const float*)d_in[0];   // [B, I, K]
    const float* W = (const float*)d_in[1];   // [J, I, D, K]
    float* out = (float*)d_out;               // [B, J, D]

    float* vT  = (float*)d_ws;                          // 40960 f32
    float* p   = vT + BB * JJ * DD;                     // 16*128*2560 f32
    short* xTb = (short*)(p + (size_t)16 * 128 * 2560); // I*B*K bf16
    short* Wb  = xTb + (size_t)II * BB * KK;            // J*I*D*K bf16
    const size_t need = (size_t)(BB * JJ * DD + 16 * 128 * 2560) * 4
                      + ((size_t)II * BB * KK + (size_t)JJ * II * DD * KK) * 2;

    if (ws_size >= need) {
        cast_w_kernel<<<(JJ * II * DD * KK / 8) / 256, 256, 0, stream>>>(W, Wb);
        trans_x_kernel<<<dim3(II / 8, BB / 32), 256, 0, stream>>>(x, xTb);

        dim3 rg(64, 16);
        dim3 sg(JJ, 16);
        // round 1: uniform c (1/J folded into squash scale)
        round_mfma<0><<<rg, 256, 0, stream>>>(xTb, Wb, vT, p);
        rs_kernel<0><<<sg, 256, 0, stream>>>(p, vT, out, 0.1f);
        // round 2: logits = v1 . U
        round_mfma<1><<<rg, 256, 0, stream>>>(xTb, Wb, vT, p);
        rs_kernel<1><<<sg, 256, 0, stream>>>(p, vT, out, 1.0f);
        // round 3: logits = (v1+v2) . U
        round_mfma<1><<<rg, 256, 0, stream>>>(xTb, Wb, vT, p);
        rs_kernel<2><<<sg, 256, 0, stream>>>(p, vT, out, 1.0f);
    } else {
        // fallback: round-1 passing path
        float* s_acc = (float*)d_ws;
        float* v_buf = s_acc + BB * JJ * DD;
        const int NS = BB * JJ * DD;
        dim3 rg(II / IT_OLD, BB / BT_OLD);
        zero_kernel<<<(NS + 255) / 256, 256, 0, stream>>>(s_acc, NS);
        round1_old<<<rg, 256, 0, stream>>>(x, W, s_acc);
        squash_old<<<(BB * JJ + 255) / 256, 256, 0, stream>>>(s_acc, v_buf, 0.1f, 0, 1);
        round_old<<<rg, 256, 0, stream>>>(x, W, v_buf, s_acc);
        squash_old<<<(BB * JJ + 255) / 256, 256, 0, stream>>>(s_acc, v_buf, 1.0f, 1, 1);
        round_old<<<rg, 256, 0, stream>>>(x, W, v_buf, s_acc);
        squash_old<<<(BB * JJ + 255) / 256, 256, 0, stream>>>(s_acc, out, 1.0f, 0, 0);
    }
}

// Round 5
// 162.474 us; speedup vs baseline: 2.2877x; 2.2877x over previous
//
#include <hip/hip_runtime.h>
#include <math.h>

// CapsuleLayer dynamic routing, fp32 in/out. B=256, I=2048, K=8, J=10, D=16.
// R5: LDS-staged MFMA rounds. Block = 4 waves = 4 b-tiles (64 b), i-chunk 16
// (2 sub-chunks of 8). W tile staged once per block (shared by all 4 waves);
// sub-chunk 1 prefetched into registers during sub-chunk 0 compute. Epilogue:
// each wave writes its own partial chunk (10x global_store_dwordx4, no atomics,
// no cross-wave reduce). NO launch_bounds VGPR cap (R4 lesson: caused spill).
// mfma_f32_16x16x32_bf16: C/D col=lane&15=b, row=(lane>>4)*4+reg=d.
// Round 1 packs 4 i's into K=32 (kc=q*8+k -> i_local=q); rounds 2/3 use kc 0..7.
// Routing logits are linear in accumulated v (round 3 uses v1+v2).
//
// ws: vT f32[40960] | p f32[16*128*2560] | xTb bf16[I*B*K] | Wb bf16[J*I*D*K] (~34.8 MB)

#define BB 256
#define II 2048
#define KK 8
#define JJ 10
#define DD 16

typedef __attribute__((ext_vector_type(4))) float f32x4;
typedef __attribute__((ext_vector_type(8))) short short8;

__device__ __forceinline__ short f2bf(float f) {
    union { float f; unsigned u; } v; v.f = f;
    unsigned r = v.u + 0x7FFFu + ((v.u >> 16) & 1u);   // RNE
    return (short)(r >> 16);
}

// W fp32 [j,i,d,k] -> Wb bf16 same layout (k contiguous = A-frag rows).
__global__ __launch_bounds__(256) void cast_w_kernel(const float* __restrict__ W,
                                                     short* __restrict__ Wb) {
    const int idx = blockIdx.x * blockDim.x + threadIdx.x;
    const float4* src = (const float4*)(W + (size_t)idx * 8);
    const float4 a = src[0], b = src[1];
    short8 o;
    o[0] = f2bf(a.x); o[1] = f2bf(a.y); o[2] = f2bf(a.z); o[3] = f2bf(a.w);
    o[4] = f2bf(b.x); o[5] = f2bf(b.y); o[6] = f2bf(b.z); o[7] = f2bf(b.w);
    *(short8*)(Wb + (size_t)idx * 8) = o;
}

// x fp32 [b,i,k] -> xTb bf16 [i,b,k], LDS-tiled, coalesced both sides.
__global__ __launch_bounds__(256) void trans_x_kernel(const float* __restrict__ x,
                                                      short* __restrict__ xTb) {
    __shared__ float4 tile[8 * 66];
    const int t = threadIdx.x;
    const int b0 = blockIdx.y * 32, i0 = blockIdx.x * 8;
    {
        const int lb = t >> 3, li = t & 7;
        const float4* src = (const float4*)(x + ((b0 + lb) * II + (i0 + li)) * KK);
        tile[li * 66 + lb * 2 + 0] = src[0];
        tile[li * 66 + lb * 2 + 1] = src[1];
    }
    __syncthreads();
    {
        const int ri = t >> 5, rb = t & 31;
        const float4 p0 = tile[ri * 66 + rb * 2 + 0];
        const float4 p1 = tile[ri * 66 + rb * 2 + 1];
        short8 o;
        o[0] = f2bf(p0.x); o[1] = f2bf(p0.y); o[2] = f2bf(p0.z); o[3] = f2bf(p0.w);
        o[4] = f2bf(p1.x); o[5] = f2bf(p1.y); o[6] = f2bf(p1.z); o[7] = f2bf(p1.w);
        *(short8*)(xTb + ((size_t)(i0 + ri) * BB + (b0 + rb)) * KK) = o;
    }
}

// ---- staging helpers: 28 segments of 1024B per sub-chunk (20 W halves + 8 x rows) ----
// LDS layout per buffer (shorts): Wl[j][il][d][k] at j*1024+il*128+d*8 ; Xl at 10240+il*512+b*8
#define LBUF 14336   // shorts per buffer

__device__ __forceinline__ void seg_src_dst(int s, int i0, int b0,
                                            const short* __restrict__ xTb,
                                            const short* __restrict__ Wb,
                                            const short** src, int* dst) {
    if (s < 20) {
        const int j = s >> 1, h = s & 1;
        *src = Wb + ((size_t)(j * II + i0) * DD) * KK + h * 512;
        *dst = j * 1024 + h * 512;
    } else {
        const int il = s - 20;
        *src = xTb + ((size_t)(i0 + il) * BB + b0) * KK;
        *dst = 10240 + il * 512;
    }
}

// One routing round. grid (128, 4), block 256 (4 waves = 4 b-tiles), 16 i per block.
// Partials p[bt][chunk=blockIdx.x][j*64 + lane] (f32x4 per lane).
template <int USE_C>
__global__ __launch_bounds__(256) void round_mfma(
    const short* __restrict__ xTb, const short* __restrict__ Wb,
    const float* __restrict__ vT, float* __restrict__ p)
{
    __shared__ short L[2][LBUF];
    const int t = threadIdx.x;
    const int lane = t & 63, wv = t >> 6;
    const int col = lane & 15, q = lane >> 4;
    const int b0 = blockIdx.y * 64;
    const int bl = wv * 16 + col;          // b within block for this wave's tile
    const int i0 = blockIdx.x * 16;

    // ---- stage sub-chunk 0, prefetch sub-chunk 1 into regs ----
    short8 r0[7], r1[7];
#pragma unroll
    for (int n = 0; n < 7; ++n) {
        const int s = wv + n * 4;          // 4 waves interleave the 28 segments
        const short* src; int dst;
        seg_src_dst(s, i0, b0, xTb, Wb, &src, &dst);
        r0[n] = *(const short8*)(src + lane * 8);
        seg_src_dst(s, i0 + 8, b0, xTb, Wb, &src, &dst);
        r1[n] = *(const short8*)(src + lane * 8);
    }
#pragma unroll
    for (int n = 0; n < 7; ++n) {
        const int s = wv + n * 4;
        const short* src; int dst;
        seg_src_dst(s, i0, b0, xTb, Wb, &src, &dst);
        *(short8*)(&L[0][dst + lane * 8]) = r0[n];
    }
    __syncthreads();

    f32x4 sfrag[JJ];
#pragma unroll
    for (int j = 0; j < JJ; ++j) sfrag[j] = (f32x4){0.f, 0.f, 0.f, 0.f};

    float vfrag[JJ][4];
    if (USE_C) {
#pragma unroll
        for (int j = 0; j < JJ; ++j)
#pragma unroll
            for (int r = 0; r < 4; ++r)
                vfrag[j][r] = vT[(j * DD + q * 4 + r) * BB + b0 + bl];
    }

#pragma unroll
    for (int sc = 0; sc < 2; ++sc) {
        const short* Lb = L[sc];
        if (USE_C) {
            for (int il = 0; il < 8; ++il) {
                short8 A[JJ], Bf;
                const short8 z = (short8){0, 0, 0, 0, 0, 0, 0, 0};
                Bf = z;
#pragma unroll
                for (int j = 0; j < JJ; ++j) A[j] = z;
                if (q == 0) {   // kc 0..7 real, quads 1..3 stay zero (k-pad 8->32)
                    Bf = *(const short8*)(&Lb[10240 + il * 512 + bl * 8]);
#pragma unroll
                    for (int j = 0; j < JJ; ++j)
                        A[j] = *(const short8*)(&Lb[j * 1024 + il * 128 + col * 8]);
                }
                f32x4 U[JJ];
#pragma unroll
                for (int j = 0; j < JJ; ++j)
                    U[j] = __builtin_amdgcn_mfma_f32_16x16x32_bf16(
                        A[j], Bf, (f32x4){0.f, 0.f, 0.f, 0.f}, 0, 0, 0);
                float Lg[JJ];
#pragma unroll
                for (int j = 0; j < JJ; ++j)
                    Lg[j] = vfrag[j][0] * U[j][0] + vfrag[j][1] * U[j][1]
                          + vfrag[j][2] * U[j][2] + vfrag[j][3] * U[j][3];
#pragma unroll
                for (int j = 0; j < JJ; ++j) {   // reduce over the 4 d-quads
                    Lg[j] += __shfl_xor(Lg[j], 16, 64);
                    Lg[j] += __shfl_xor(Lg[j], 32, 64);
                }
                float sum = 0.f;   // |logit| is O(1): no max-subtraction needed
#pragma unroll
                for (int j = 0; j < JJ; ++j) { Lg[j] = __expf(Lg[j]); sum += Lg[j]; }
                const float inv = __builtin_amdgcn_rcpf(sum);
#pragma unroll
                for (int j = 0; j < JJ; ++j) {
                    const float c = Lg[j] * inv;
#pragma unroll
                    for (int r = 0; r < 4; ++r) sfrag[j][r] += c * U[j][r];
                }
            }
        } else {
            // round 1: sum_i U. Pack 4 i's per MFMA: kc = q*8 + k -> i_local = q.
#pragma unroll
            for (int s = 0; s < 2; ++s) {
                const int il = s * 4 + q;
                const short8 Bf = *(const short8*)(&Lb[10240 + il * 512 + bl * 8]);
#pragma unroll
                for (int j = 0; j < JJ; ++j) {
                    const short8 A = *(const short8*)(&Lb[j * 1024 + il * 128 + col * 8]);
                    sfrag[j] = __builtin_amdgcn_mfma_f32_16x16x32_bf16(A, Bf, sfrag[j], 0, 0, 0);
                }
            }
        }
        if (sc == 0) {   // publish sub-chunk 1 (regs were loaded before compute 0)
#pragma unroll
            for (int n = 0; n < 7; ++n) {
                const int s = wv + n * 4;
                const short* src; int dst;
                seg_src_dst(s, i0 + 8, b0, xTb, Wb, &src, &dst);
                *(short8*)(&L[1][dst + lane * 8]) = r1[n];
            }
            __syncthreads();
        }
    }

    // epilogue: wave-private partial chunk, 10 coalesced 16B stores
    float* pp = p + ((size_t)(blockIdx.y * 4 + wv) * 128 + blockIdx.x) * (JJ * 256);
#pragma unroll
    for (int j = 0; j < JJ; ++j)
        *(f32x4*)(pp + (j * 64 + lane) * 4) = sfrag[j];
}

// Fused reduce + squash. grid (10 j, 16 bt), block 256 (t = d*16 + bc).
// p element (j,d,bc) lives at j*256 + lane*4 + r, lane=(d>>2)*16+bc, r=d&3.
// MODE 0: vT = squash(scale*s)   MODE 1: vT += squash(s)   MODE 2: out = squash(s)
template <int MODE>
__global__ __launch_bounds__(256) void rs_kernel(const float* __restrict__ p,
                                                 float* __restrict__ vT,
                                                 float* __restrict__ out, float scale) {
    __shared__ float red[256];
    __shared__ float cf[16];
    const int t = threadIdx.x;
    const int j = blockIdx.x, bt = blockIdx.y;
    const int d = t >> 4, bc = t & 15;
    const int lane = (d >> 2) * 16 + bc, r = d & 3;

    const float* pp = p + (size_t)bt * 128 * (JJ * 256) + j * 256 + lane * 4 + r;
    float sum = 0.f;
#pragma unroll 8
    for (int ch = 0; ch < 128; ++ch) sum += pp[(size_t)ch * (JJ * 256)];
    const float s = sum * scale;

    red[t] = s;
    __syncthreads();
    if (t < 16) {
        float ss = 0.f;
#pragma unroll
        for (int dd = 0; dd < DD; ++dd) {
            const float v = red[dd * 16 + t];
            ss += v * v;
        }
        cf[t] = ss / (1.f + ss) / sqrtf(ss + 1e-7f);
    }
    __syncthreads();
    const float v = cf[bc] * s;
    if (MODE == 0) vT[(j * DD + d) * BB + bt * 16 + bc] = v;
    if (MODE == 1) vT[(j * DD + d) * BB + bt * 16 + bc] += v;
    if (MODE == 2) out[((bt * 16 + bc) * JJ + j) * DD + d] = v;
}

// ---------------- fallback path (round-1 passing kernel, 365us) ----------------
#define IT_OLD 32
#define BT_OLD 16

__global__ __launch_bounds__(256) void zero_kernel(float* __restrict__ p, int n) {
    int idx = blockIdx.x * blockDim.x + threadIdx.x;
    if (idx < n) p[idx] = 0.f;
}

__global__ __launch_bounds__(256) void squash_old(float* __restrict__ s_acc,
                                                  float* __restrict__ dst, float scale,
                                                  int add_to_dst, int zero_src) {
    int idx = blockIdx.x * blockDim.x + threadIdx.x;
    if (idx >= BB * JJ) return;
    float s[DD];
    float ss = 0.f;
#pragma unroll
    for (int d = 0; d < DD; ++d) {
        s[d] = s_acc[idx * DD + d] * scale;
        ss += s[d] * s[d];
    }
    const float coef = ss / (1.f + ss) / sqrtf(ss + 1e-7f);
#pragma unroll
    for (int d = 0; d < DD; ++d) {
        const float vv = coef * s[d];
        if (add_to_dst) dst[idx * DD + d] += vv;
        else            dst[idx * DD + d] = vv;
        if (zero_src)   s_acc[idx * DD + d] = 0.f;
    }
}

__global__ __launch_bounds__(256) void round1_old(const float* __restrict__ x,
                                                  const float* __restrict__ W,
                                                  float* __restrict__ s_acc) {
    const int t = threadIdx.x;
    const int d = t & 15;
    const int bq = t >> 4;
    const int b = blockIdx.y * BT_OLD + bq;
    const int i0 = blockIdx.x * IT_OLD;
    float acc[JJ];
#pragma unroll
    for (int j = 0; j < JJ; ++j) acc[j] = 0.f;
    for (int ii = 0; ii < IT_OLD; ++ii) {
        const int i = i0 + ii;
        const float* xp = x + ((b * II) + i) * KK;
        const float4 xa = *(const float4*)(xp);
        const float4 xb = *(const float4*)(xp + 4);
#pragma unroll
        for (int j = 0; j < JJ; ++j) {
            const float* wp = W + (((j * II + i) * DD + d) * KK);
            const float4 w0 = *(const float4*)(wp);
            const float4 w1 = *(const float4*)(wp + 4);
            acc[j] += w0.x*xa.x + w0.y*xa.y + w0.z*xa.z + w0.w*xa.w
                    + w1.x*xb.x + w1.y*xb.y + w1.z*xb.z + w1.w*xb.w;
        }
    }
#pragma unroll
    for (int j = 0; j < JJ; ++j)
        atomicAdd(&s_acc[(b * JJ + j) * DD + d], acc[j]);
}

__global__ __launch_bounds__(256) void round_old(const float* __restrict__ x,
                                                 const float* __restrict__ W,
                                                 const float* __restrict__ v,
                                                 float* __restrict__ s_acc) {
    const int t = threadIdx.x;
    const int d = t & 15;
    const int bq = t >> 4;
    const int b = blockIdx.y * BT_OLD + bq;
    const int i0 = blockIdx.x * IT_OLD;
    float vr[JJ], acc[JJ];
#pragma unroll
    for (int j = 0; j < JJ; ++j) {
        vr[j] = v[(b * JJ + j) * DD + d];
        acc[j] = 0.f;
    }
    for (int ii = 0; ii < IT_OLD; ++ii) {
        const int i = i0 + ii;
        const float* xp = x + ((b * II) + i) * KK;
        const float4 xa = *(const float4*)(xp);
        const float4 xb = *(const float4*)(xp + 4);
        float U[JJ], Lg[JJ];
#pragma unroll
        for (int j = 0; j < JJ; ++j) {
            const float* wp = W + (((j * II + i) * DD + d) * KK);
            const float4 w0 = *(const float4*)(wp);
            const float4 w1 = *(const float4*)(wp + 4);
            U[j] = w0.x*xa.x + w0.y*xa.y + w0.z*xa.z + w0.w*xa.w
                 + w1.x*xb.x + w1.y*xb.y + w1.z*xb.z + w1.w*xb.w;
            Lg[j] = vr[j] * U[j];
        }
#pragma unroll
        for (int m = 8; m >= 1; m >>= 1) {
#pragma unroll
            for (int j = 0; j < JJ; ++j) Lg[j] += __shfl_xor(Lg[j], m, 64);
        }
        float mx = Lg[0];
#pragma unroll
        for (int j = 1; j < JJ; ++j) mx = fmaxf(mx, Lg[j]);
        float sum = 0.f;
#pragma unroll
        for (int j = 0; j < JJ; ++j) { Lg[j] = __expf(Lg[j] - mx); sum += Lg[j]; }
        const float inv = 1.f / sum;
#pragma unroll
        for (int j = 0; j < JJ; ++j) acc[j] += (Lg[j] * inv) * U[j];
    }
#pragma unroll
    for (int j = 0; j < JJ; ++j)
        atomicAdd(&s_acc[(b * JJ + j) * DD + d], acc[j]);
}

extern "C" void kernel_launch(void* const* d_in, const int* in_sizes, int n_in,
                              void* d_out, int out_size, void* d_ws, size_t ws_size,
                              hipStream_t stream) {
    const float* x = (const float*)d_in[0];   // [B, I, K]
    const float* W = (const float*)d_in[1];   // [J, I, D, K]
    float* out = (float*)d_out;               // [B, J, D]

    float* vT  = (float*)d_ws;                          // 40960 f32
    float* p   = vT + BB * JJ * DD;                     // 16*128*2560 f32
    short* xTb = (short*)(p + (size_t)16 * 128 * 2560); // I*B*K bf16
    short* Wb  = xTb + (size_t)II * BB * KK;            // J*I*D*K bf16
    const size_t need = (size_t)(BB * JJ * DD + 16 * 128 * 2560) * 4
                      + ((size_t)II * BB * KK + (size_t)JJ * II * DD * KK) * 2;

    if (ws_size >= need) {
        cast_w_kernel<<<(JJ * II * DD * KK / 8) / 256, 256, 0, stream>>>(W, Wb);
        trans_x_kernel<<<dim3(II / 8, BB / 32), 256, 0, stream>>>(x, xTb);

        dim3 rg(128, 4);
        dim3 sg(JJ, 16);
        // round 1: uniform c (1/J folded into squash scale)
        round_mfma<0><<<rg, 256, 0, stream>>>(xTb, Wb, vT, p);
        rs_kernel<0><<<sg, 256, 0, stream>>>(p, vT, out, 0.1f);
        // round 2: logits = v1 . U
        round_mfma<1><<<rg, 256, 0, stream>>>(xTb, Wb, vT, p);
        rs_kernel<1><<<sg, 256, 0, stream>>>(p, vT, out, 1.0f);
        // round 3: logits = (v1+v2) . U
        round_mfma<1><<<rg, 256, 0, stream>>>(xTb, Wb, vT, p);
        rs_kernel<2><<<sg, 256, 0, stream>>>(p, vT, out, 1.0f);
    } else {
        // fallback: round-1 passing path
        float* s_acc = (float*)d_ws;
        float* v_buf = s_acc + BB * JJ * DD;
        const int NS = BB * JJ * DD;
        dim3 rg(II / IT_OLD, BB / BT_OLD);
        zero_kernel<<<(NS + 255) / 256, 256, 0, stream>>>(s_acc, NS);
        round1_old<<<rg, 256, 0, stream>>>(x, W, s_acc);
        squash_old<<<(BB * JJ + 255) / 256, 256, 0, stream>>>(s_acc, v_buf, 0.1f, 0, 1);
        round_old<<<rg, 256, 0, stream>>>(x, W, v_buf, s_acc);
        squash_old<<<(BB * JJ + 255) / 256, 256, 0, stream>>>(s_acc, v_buf, 1.0f, 1, 1);
        round_old<<<rg, 256, 0, stream>>>(x, W, v_buf, s_acc);
        squash_old<<<(BB * JJ + 255) / 256, 256, 0, stream>>>(s_acc, out, 1.0f, 0, 0);
    }
}